// Round 2
// baseline (928.354 us; speedup 1.0000x reference)
//
#include <hip/hip_runtime.h>
#include <math.h>

#define DIM 4096
#define NH 32
#define NKV 8
#define HD 128
#define BATCH 32
#define CL 2176
#define QKV_DIM 6144  // (32 + 2*8) * 128
#define NREP 4

// ---------------------------------------------------------------------------
// Kernel: k-split GEMV-style GEMM partial.  C_part[kc][b][n] = sum over 128 k.
// grid (N/256, 32), block 256.  x is [32][DIM] row-major, w is [DIM][N].
// x reads are wave-uniform (scalar-load / broadcast).  VALU-bound at ~fp32 peak.
// ---------------------------------------------------------------------------
template<int N>
__global__ __launch_bounds__(256) void gemm_partial(const float* __restrict__ x,
                                                    const float* __restrict__ w,
                                                    float* __restrict__ part) {
    const int t = threadIdx.x;
    const int n0 = blockIdx.x * 256;
    const int k0 = blockIdx.y * 128;

    float acc[32];
#pragma unroll
    for (int b = 0; b < 32; ++b) acc[b] = 0.f;

    const float* wp = w + (size_t)k0 * N + n0 + t;
    const float* xp = x + k0;

    for (int kk = 0; kk < 128; kk += 4) {
        const float wv0 = wp[(size_t)(kk + 0) * N];
        const float wv1 = wp[(size_t)(kk + 1) * N];
        const float wv2 = wp[(size_t)(kk + 2) * N];
        const float wv3 = wp[(size_t)(kk + 3) * N];
#pragma unroll
        for (int b = 0; b < 32; ++b) {
            const float4 xv = *(const float4*)(xp + (size_t)b * DIM + kk);  // uniform
            acc[b] = fmaf(xv.x, wv0, acc[b]);
            acc[b] = fmaf(xv.y, wv1, acc[b]);
            acc[b] = fmaf(xv.z, wv2, acc[b]);
            acc[b] = fmaf(xv.w, wv3, acc[b]);
        }
    }

    float* pp = part + (size_t)blockIdx.y * 32 * N + n0 + t;
#pragma unroll
    for (int b = 0; b < 32; ++b) pp[(size_t)b * N] = acc[b];
}

// ---------------------------------------------------------------------------
// Kernel: fully fused attention.  grid 256 (bg), block 1024 (16 waves).
// Per block:  (1) reduce QKV partials for this (b,g) + RoPE  ->  q,k_new,v_new
//             (2) QK^T: ONE ROW PER LANE, Q via LDS broadcast -> zero shfls
//             (3) softmax in LDS (no HBM round-trip)
//             (4) P@V with prob broadcast from LDS
// LDS ~41.5 KB.  Scores buffer reused for the output reduction.
// ---------------------------------------------------------------------------
__global__ __launch_bounds__(1024) void attn_fused(const float* __restrict__ part,
                                                   const float* __restrict__ cache_k,
                                                   const float* __restrict__ cache_v,
                                                   const int* __restrict__ sp_p,
                                                   float* __restrict__ attn) {
    const int bg = blockIdx.x;
    const int b = bg >> 3, g = bg & 7;
    const int sp = *sp_p;
    const int t = threadIdx.x;
    const int w = t >> 6, lane = t & 63;
    const int grp = t >> 5, sl = t & 31, half = grp & 1;

    __shared__ float sc[CL * 4];       // scores -> probs [s][4h]; reused for out-reduce
    __shared__ float q_s[4 * HD];      // 4 q heads, pre-scaled by 1/sqrt(HD)
    __shared__ float k_s[HD];          // roped new K row
    __shared__ float v_s[HD];          // new V row
    __shared__ float raw[6 * HD];      // pre-RoPE sums
    __shared__ float redm[16 * 4];
    __shared__ float redl[16 * 4];
    __shared__ float s_inv[4];

    const float scale = 0.08838834764831845f;  // 1/sqrt(128)

    // ---- (1) QKV finish: reduce 32 k-chunk partials for this block's 6 heads ----
    if (t < 768) {
        const int hl = t >> 7, d = t & 127;
        int col;
        if (hl < 4)       col = g * 512 + t;          // q heads g*4 .. g*4+3
        else if (hl == 4) col = 4096 + g * 128 + d;   // k head
        else              col = 5120 + g * 128 + d;   // v head
        const float* pp = part + (size_t)b * QKV_DIM + col;
        float s = 0.f;
        for (int kc = 0; kc < 32; ++kc)
            s += pp[(size_t)kc * 32 * QKV_DIM];
        raw[t] = s;
    }
    __syncthreads();
    if (t < 768) {
        const int hl = t >> 7, d = t & 127;
        float s = raw[t];
        float outv = s;
        if (hl < 5) {  // q and k get RoPE
            int j = d & 63;
            float inv_freq = powf(10000.0f, -(float)(2 * j) / 128.0f);
            float ang = (float)sp * inv_freq;
            float c = cosf(ang), sn = sinf(ang);
            int base = t & ~127;
            float rot = (d < 64) ? -raw[base + d + 64] : raw[base + d - 64];
            outv = s * c + rot * sn;
        }
        if (hl < 4)       q_s[t] = outv * scale;   // fold score scale into q
        else if (hl == 4) k_s[d] = outv;
        else              v_s[d] = outv;
    }
    __syncthreads();

    // ---- (2) QK^T: one s-row per lane, two rows per pass.  Q broadcast from LDS ----
    const float* kbase = cache_k + ((size_t)b * NKV + g) * (size_t)CL * HD;
    for (int sA = t; sA < sp; sA += 2048) {
        const int sB = sA + 1024;
        const bool hasB = (sB < sp);
        const float* krA = kbase + (size_t)sA * HD;
        const float* krB = kbase + (size_t)sB * HD;
        float pA0 = 0.f, pA1 = 0.f, pA2 = 0.f, pA3 = 0.f;
        float pB0 = 0.f, pB1 = 0.f, pB2 = 0.f, pB3 = 0.f;
#pragma unroll 4
        for (int kk = 0; kk < HD; kk += 4) {
            const float4 q0 = *(const float4*)&q_s[0 * HD + kk];  // uniform -> broadcast
            const float4 q1 = *(const float4*)&q_s[1 * HD + kk];
            const float4 q2 = *(const float4*)&q_s[2 * HD + kk];
            const float4 q3 = *(const float4*)&q_s[3 * HD + kk];
            const float4 ka = *(const float4*)(krA + kk);
            pA0 += q0.x * ka.x + q0.y * ka.y + q0.z * ka.z + q0.w * ka.w;
            pA1 += q1.x * ka.x + q1.y * ka.y + q1.z * ka.z + q1.w * ka.w;
            pA2 += q2.x * ka.x + q2.y * ka.y + q2.z * ka.z + q2.w * ka.w;
            pA3 += q3.x * ka.x + q3.y * ka.y + q3.z * ka.z + q3.w * ka.w;
            if (hasB) {
                const float4 kb = *(const float4*)(krB + kk);
                pB0 += q0.x * kb.x + q0.y * kb.y + q0.z * kb.z + q0.w * kb.w;
                pB1 += q1.x * kb.x + q1.y * kb.y + q1.z * kb.z + q1.w * kb.w;
                pB2 += q2.x * kb.x + q2.y * kb.y + q2.z * kb.z + q2.w * kb.w;
                pB3 += q3.x * kb.x + q3.y * kb.y + q3.z * kb.z + q3.w * kb.w;
            }
        }
        *(float4*)&sc[(size_t)sA * 4] = make_float4(pA0, pA1, pA2, pA3);
        if (hasB) *(float4*)&sc[(size_t)sB * 4] = make_float4(pB0, pB1, pB2, pB3);
    }
    // the s == sp row uses the freshly-roped K from LDS (4 threads, 1 head each)
    if (t < 4) {
        float p = 0.f;
        for (int k = 0; k < HD; ++k) p += q_s[t * HD + k] * k_s[k];
        sc[(size_t)sp * 4 + t] = p;
    }
    __syncthreads();

    // ---- (3) softmax over s in [0, sp], per head, entirely in LDS ----
    float m[4] = {-1e30f, -1e30f, -1e30f, -1e30f};
    for (int s = t; s <= sp; s += 1024) {
        const float4 v = *(const float4*)&sc[(size_t)s * 4];
        m[0] = fmaxf(m[0], v.x);
        m[1] = fmaxf(m[1], v.y);
        m[2] = fmaxf(m[2], v.z);
        m[3] = fmaxf(m[3], v.w);
    }
#pragma unroll
    for (int off = 1; off < 64; off <<= 1) {
#pragma unroll
        for (int h = 0; h < 4; ++h) m[h] = fmaxf(m[h], __shfl_xor(m[h], off));
    }
    if (lane == 0) {
#pragma unroll
        for (int h = 0; h < 4; ++h) redm[w * 4 + h] = m[h];
    }
    __syncthreads();
#pragma unroll
    for (int h = 0; h < 4; ++h) {
        float mm = redm[h];
        for (int ww = 1; ww < 16; ++ww) mm = fmaxf(mm, redm[ww * 4 + h]);
        m[h] = mm;
    }

    float l[4] = {0.f, 0.f, 0.f, 0.f};
    for (int s = t; s <= sp; s += 1024) {
        float4 v = *(const float4*)&sc[(size_t)s * 4];
        v.x = expf(v.x - m[0]);
        v.y = expf(v.y - m[1]);
        v.z = expf(v.z - m[2]);
        v.w = expf(v.w - m[3]);
        *(float4*)&sc[(size_t)s * 4] = v;
        l[0] += v.x; l[1] += v.y; l[2] += v.z; l[3] += v.w;
    }
#pragma unroll
    for (int off = 1; off < 64; off <<= 1) {
#pragma unroll
        for (int h = 0; h < 4; ++h) l[h] += __shfl_xor(l[h], off);
    }
    if (lane == 0) {
#pragma unroll
        for (int h = 0; h < 4; ++h) redl[w * 4 + h] = l[h];
    }
    __syncthreads();  // probs complete + redl complete
    if (t == 0) {
        float l0 = 0.f, l1 = 0.f, l2 = 0.f, l3 = 0.f;
        for (int ww = 0; ww < 16; ++ww) {
            l0 += redl[ww * 4 + 0]; l1 += redl[ww * 4 + 1];
            l2 += redl[ww * 4 + 2]; l3 += redl[ww * 4 + 3];
        }
        s_inv[0] = 1.f / l0; s_inv[1] = 1.f / l1;
        s_inv[2] = 1.f / l2; s_inv[3] = 1.f / l3;
    }

    // ---- (4) P @ V: 32 lane-groups stride over s; probs broadcast from LDS ----
    const float* vbase = cache_v + ((size_t)b * NKV + g) * (size_t)CL * HD;
    float o[4][4];
#pragma unroll
    for (int h = 0; h < 4; ++h)
#pragma unroll
        for (int c = 0; c < 4; ++c) o[h][c] = 0.f;

    for (int s = grp; s < sp; s += 32) {
        const float4 vv = *(const float4*)(vbase + (size_t)s * HD + sl * 4);
        const float4 pp = *(const float4*)&sc[(size_t)s * 4];  // group-broadcast
        o[0][0] += pp.x * vv.x; o[0][1] += pp.x * vv.y; o[0][2] += pp.x * vv.z; o[0][3] += pp.x * vv.w;
        o[1][0] += pp.y * vv.x; o[1][1] += pp.y * vv.y; o[1][2] += pp.y * vv.z; o[1][3] += pp.y * vv.w;
        o[2][0] += pp.z * vv.x; o[2][1] += pp.z * vv.y; o[2][2] += pp.z * vv.z; o[2][3] += pp.z * vv.w;
        o[3][0] += pp.w * vv.x; o[3][1] += pp.w * vv.y; o[3][2] += pp.w * vv.z; o[3][3] += pp.w * vv.w;
    }
    if ((sp & 31) == grp) {  // the new V row, owned by exactly one group
        const float4 pp = *(const float4*)&sc[(size_t)sp * 4];
        const float4 vv = *(const float4*)&v_s[sl * 4];
        o[0][0] += pp.x * vv.x; o[0][1] += pp.x * vv.y; o[0][2] += pp.x * vv.z; o[0][3] += pp.x * vv.w;
        o[1][0] += pp.y * vv.x; o[1][1] += pp.y * vv.y; o[1][2] += pp.y * vv.z; o[1][3] += pp.y * vv.w;
        o[2][0] += pp.z * vv.x; o[2][1] += pp.z * vv.y; o[2][2] += pp.z * vv.z; o[2][3] += pp.z * vv.w;
        o[3][0] += pp.w * vv.x; o[3][1] += pp.w * vv.y; o[3][2] += pp.w * vv.z; o[3][3] += pp.w * vv.w;
    }

    // fold the two 32-lane halves of each wave in-register
#pragma unroll
    for (int h = 0; h < 4; ++h)
#pragma unroll
        for (int c = 0; c < 4; ++c) o[h][c] += __shfl_xor(o[h][c], 32);

    __syncthreads();  // all prob reads done; reuse sc as reduction buffer

    if (half == 0) {
#pragma unroll
        for (int h = 0; h < 4; ++h)
            *(float4*)&sc[w * 512 + h * 128 + sl * 4] =
                make_float4(o[h][0], o[h][1], o[h][2], o[h][3]);
    }
    __syncthreads();

    for (int step = 8; step >= 1; step >>= 1) {
        if (w < step) {
#pragma unroll
            for (int i = 0; i < 8; ++i) {
                int j = lane + i * 64;
                sc[w * 512 + j] += sc[(w + step) * 512 + j];
            }
        }
        __syncthreads();
    }

    if (t < 512) {
        int h = t >> 7, d = t & 127;
        attn[(size_t)b * DIM + (g * 4 + h) * 128 + d] = sc[h * 128 + d] * s_inv[h];
    }
}

// ---------------------------------------------------------------------------
// Kernel: final reduce of output-projection partials.  grid 512, block 256.
// ---------------------------------------------------------------------------
__global__ void out_reduce(const float* __restrict__ part, float* __restrict__ out) {
    const int e = blockIdx.x * 256 + threadIdx.x;
    float s = 0.f;
    for (int kc = 0; kc < 32; ++kc) s += part[(size_t)kc * 32 * DIM + e];
    out[e] = s;
}

// ---------------------------------------------------------------------------
extern "C" void kernel_launch(void* const* d_in, const int* in_sizes, int n_in,
                              void* d_out, int out_size, void* d_ws, size_t ws_size,
                              hipStream_t stream) {
    const float* x       = (const float*)d_in[0];
    const float* wqkv    = (const float*)d_in[1];
    const float* wo      = (const float*)d_in[2];
    const float* cache_k = (const float*)d_in[3];
    const float* cache_v = (const float*)d_in[4];
    const int*   sp      = (const int*)d_in[5];
    float* out = (float*)d_out;
    float* ws  = (float*)d_ws;

    // workspace layout (floats)
    float* part1  = ws;                       // 32*32*6144 = 6,291,456
    float* attn   = part1 + 6291456;          // 32*4096    =   131,072
    float* part2  = attn + 131072;            // 32*32*4096 = 4,194,304
    // total 10,616,832 floats = 42.5 MB

    gemm_partial<QKV_DIM><<<dim3(24, 32), 256, 0, stream>>>(x, wqkv, part1);
    attn_fused<<<256, 1024, 0, stream>>>(part1, cache_k, cache_v, sp, attn);
    gemm_partial<DIM><<<dim3(16, 32), 256, 0, stream>>>(attn, wo, part2);
    out_reduce<<<512, 256, 0, stream>>>(part2, out);
}

// Round 3
// 783.541 us; speedup vs baseline: 1.1848x; 1.1848x over previous
//
#include <hip/hip_runtime.h>
#include <math.h>

#define DIM 4096
#define NH 32
#define NKV 8
#define HD 128
#define BATCH 32
#define CL 2176
#define QKV_DIM 6144  // (32 + 2*8) * 128
#define NREP 4

// ---------------------------------------------------------------------------
// Kernel: k-split GEMV-style GEMM partial.  C_part[kc][b][n] = sum over 128 k.
// grid (N/256, 32), block 256.  x is [32][DIM] row-major, w is [DIM][N].
// x reads are wave-uniform (scalar/broadcast).  w reads software-pipelined
// one quad ahead so HBM latency hides under the 128-FMA block.
// ---------------------------------------------------------------------------
template<int N>
__global__ __launch_bounds__(256) void gemm_partial(const float* __restrict__ x,
                                                    const float* __restrict__ w,
                                                    float* __restrict__ part) {
    const int t = threadIdx.x;
    const int n0 = blockIdx.x * 256;
    const int k0 = blockIdx.y * 128;

    float acc[32];
#pragma unroll
    for (int b = 0; b < 32; ++b) acc[b] = 0.f;

    const float* wp = w + (size_t)k0 * N + n0 + t;
    const float* xp = x + k0;

    float cw0 = wp[0];
    float cw1 = wp[(size_t)1 * N];
    float cw2 = wp[(size_t)2 * N];
    float cw3 = wp[(size_t)3 * N];

    for (int kk = 0; kk < 128; kk += 4) {
        float nw0, nw1, nw2, nw3;
        if (kk + 4 < 128) {  // prefetch next w quad while FMAs run
            const float* np = wp + (size_t)(kk + 4) * N;
            nw0 = np[0];
            nw1 = np[(size_t)1 * N];
            nw2 = np[(size_t)2 * N];
            nw3 = np[(size_t)3 * N];
        }
#pragma unroll
        for (int b = 0; b < 32; ++b) {
            const float4 xv = *(const float4*)(xp + (size_t)b * DIM + kk);  // uniform
            acc[b] = fmaf(xv.x, cw0, acc[b]);
            acc[b] = fmaf(xv.y, cw1, acc[b]);
            acc[b] = fmaf(xv.z, cw2, acc[b]);
            acc[b] = fmaf(xv.w, cw3, acc[b]);
        }
        if (kk + 4 < 128) { cw0 = nw0; cw1 = nw1; cw2 = nw2; cw3 = nw3; }
    }

    float* pp = part + (size_t)blockIdx.y * 32 * N + n0 + t;
#pragma unroll
    for (int b = 0; b < 32; ++b) pp[(size_t)b * N] = acc[b];
}

// ---------------------------------------------------------------------------
// Kernel: fully fused attention.  grid 256 (bg), block 1024 (16 waves).
// Per block:  (1) reduce QKV partials for this (b,g) + RoPE  ->  q,k_new,v_new
//             (2) QK^T: 4-LANE CLUSTER per K row -- each lane reads a float4
//                 of a fully-consumed 64B line (coalesced, no L1 thrash);
//                 dot reduced with 2 shfl_xor steps x 4 heads = 8 shfl/row
//             (3) softmax in LDS (no HBM round-trip)
//             (4) P@V with prob broadcast from LDS
// LDS ~41.5 KB.  Scores buffer reused for the output reduction.
// ---------------------------------------------------------------------------
__global__ __launch_bounds__(1024) void attn_fused(const float* __restrict__ part,
                                                   const float* __restrict__ cache_k,
                                                   const float* __restrict__ cache_v,
                                                   const int* __restrict__ sp_p,
                                                   float* __restrict__ attn) {
    const int bg = blockIdx.x;
    const int b = bg >> 3, g = bg & 7;
    const int sp = *sp_p;
    const int t = threadIdx.x;
    const int w = t >> 6, lane = t & 63;
    const int grp = t >> 5, sl = t & 31, half = grp & 1;

    __shared__ float sc[CL * 4];       // scores -> probs [s][4h]; reused for out-reduce
    __shared__ float q_s[4 * HD];      // 4 q heads, pre-scaled by 1/sqrt(HD)
    __shared__ float k_s[HD];          // roped new K row
    __shared__ float v_s[HD];          // new V row
    __shared__ float raw[6 * HD];      // pre-RoPE sums
    __shared__ float redm[16 * 4];
    __shared__ float redl[16 * 4];
    __shared__ float s_inv[4];

    const float scale = 0.08838834764831845f;  // 1/sqrt(128)

    // ---- (1) QKV finish: reduce 32 k-chunk partials for this block's 6 heads ----
    if (t < 768) {
        const int hl = t >> 7, d = t & 127;
        int col;
        if (hl < 4)       col = g * 512 + t;          // q heads g*4 .. g*4+3
        else if (hl == 4) col = 4096 + g * 128 + d;   // k head
        else              col = 5120 + g * 128 + d;   // v head
        const float* pp = part + (size_t)b * QKV_DIM + col;
        float s = 0.f;
        for (int kc = 0; kc < 32; ++kc)
            s += pp[(size_t)kc * 32 * QKV_DIM];
        raw[t] = s;
    }
    __syncthreads();
    if (t < 768) {
        const int hl = t >> 7, d = t & 127;
        float s = raw[t];
        float outv = s;
        if (hl < 5) {  // q and k get RoPE
            int j = d & 63;
            float inv_freq = powf(10000.0f, -(float)(2 * j) / 128.0f);
            float ang = (float)sp * inv_freq;
            float c = cosf(ang), sn = sinf(ang);
            int base = t & ~127;
            float rot = (d < 64) ? -raw[base + d + 64] : raw[base + d - 64];
            outv = s * c + rot * sn;
        }
        if (hl < 4)       q_s[t] = outv * scale;   // fold score scale into q
        else if (hl == 4) k_s[d] = outv;
        else              v_s[d] = outv;
    }
    __syncthreads();

    // ---- (2) QK^T: 4-lane cluster per row; coalesced 64B-line reads ----
    const int cl = t & 3;          // lane within cluster (covers kk = j*16 + cl*4)
    const int cr = t >> 2;         // cluster id 0..255
    const float* kbase = cache_k + ((size_t)b * NKV + g) * (size_t)CL * HD;

    for (int s = cr; s < sp; s += 256) {
        const float* krow = kbase + (size_t)s * HD;
        float p0 = 0.f, p1 = 0.f, p2 = 0.f, p3 = 0.f;
#pragma unroll
        for (int j = 0; j < 8; ++j) {
            const int kk = j * 16 + cl * 4;
            const float4 kv = *(const float4*)(krow + kk);
            const float4 q0 = *(const float4*)&q_s[0 * HD + kk];
            const float4 q1 = *(const float4*)&q_s[1 * HD + kk];
            const float4 q2 = *(const float4*)&q_s[2 * HD + kk];
            const float4 q3 = *(const float4*)&q_s[3 * HD + kk];
            p0 += q0.x * kv.x + q0.y * kv.y + q0.z * kv.z + q0.w * kv.w;
            p1 += q1.x * kv.x + q1.y * kv.y + q1.z * kv.z + q1.w * kv.w;
            p2 += q2.x * kv.x + q2.y * kv.y + q2.z * kv.z + q2.w * kv.w;
            p3 += q3.x * kv.x + q3.y * kv.y + q3.z * kv.z + q3.w * kv.w;
        }
        // reduce each head's partial across the 4 cluster lanes
        p0 += __shfl_xor(p0, 1); p0 += __shfl_xor(p0, 2);
        p1 += __shfl_xor(p1, 1); p1 += __shfl_xor(p1, 2);
        p2 += __shfl_xor(p2, 1); p2 += __shfl_xor(p2, 2);
        p3 += __shfl_xor(p3, 1); p3 += __shfl_xor(p3, 2);
        const float pv = (cl == 0) ? p0 : (cl == 1) ? p1 : (cl == 2) ? p2 : p3;
        sc[s * 4 + cl] = pv;
    }
    // the s == sp row uses the freshly-roped K from LDS (4 threads, 1 head each)
    if (t < 4) {
        float p = 0.f;
        for (int k = 0; k < HD; ++k) p += q_s[t * HD + k] * k_s[k];
        sc[(size_t)sp * 4 + t] = p;
    }
    __syncthreads();

    // ---- (3) softmax over s in [0, sp], per head, entirely in LDS ----
    float m[4] = {-1e30f, -1e30f, -1e30f, -1e30f};
    for (int s = t; s <= sp; s += 1024) {
        const float4 v = *(const float4*)&sc[(size_t)s * 4];
        m[0] = fmaxf(m[0], v.x);
        m[1] = fmaxf(m[1], v.y);
        m[2] = fmaxf(m[2], v.z);
        m[3] = fmaxf(m[3], v.w);
    }
#pragma unroll
    for (int off = 1; off < 64; off <<= 1) {
#pragma unroll
        for (int h = 0; h < 4; ++h) m[h] = fmaxf(m[h], __shfl_xor(m[h], off));
    }
    if (lane == 0) {
#pragma unroll
        for (int h = 0; h < 4; ++h) redm[w * 4 + h] = m[h];
    }
    __syncthreads();
#pragma unroll
    for (int h = 0; h < 4; ++h) {
        float mm = redm[h];
        for (int ww = 1; ww < 16; ++ww) mm = fmaxf(mm, redm[ww * 4 + h]);
        m[h] = mm;
    }

    float l[4] = {0.f, 0.f, 0.f, 0.f};
    for (int s = t; s <= sp; s += 1024) {
        float4 v = *(const float4*)&sc[(size_t)s * 4];
        v.x = expf(v.x - m[0]);
        v.y = expf(v.y - m[1]);
        v.z = expf(v.z - m[2]);
        v.w = expf(v.w - m[3]);
        *(float4*)&sc[(size_t)s * 4] = v;
        l[0] += v.x; l[1] += v.y; l[2] += v.z; l[3] += v.w;
    }
#pragma unroll
    for (int off = 1; off < 64; off <<= 1) {
#pragma unroll
        for (int h = 0; h < 4; ++h) l[h] += __shfl_xor(l[h], off);
    }
    if (lane == 0) {
#pragma unroll
        for (int h = 0; h < 4; ++h) redl[w * 4 + h] = l[h];
    }
    __syncthreads();  // probs complete + redl complete
    if (t == 0) {
        float l0 = 0.f, l1 = 0.f, l2 = 0.f, l3 = 0.f;
        for (int ww = 0; ww < 16; ++ww) {
            l0 += redl[ww * 4 + 0]; l1 += redl[ww * 4 + 1];
            l2 += redl[ww * 4 + 2]; l3 += redl[ww * 4 + 3];
        }
        s_inv[0] = 1.f / l0; s_inv[1] = 1.f / l1;
        s_inv[2] = 1.f / l2; s_inv[3] = 1.f / l3;
    }

    // ---- (4) P @ V: 32 lane-groups stride over s; probs broadcast from LDS ----
    const float* vbase = cache_v + ((size_t)b * NKV + g) * (size_t)CL * HD;
    float o[4][4];
#pragma unroll
    for (int h = 0; h < 4; ++h)
#pragma unroll
        for (int c = 0; c < 4; ++c) o[h][c] = 0.f;

    for (int s = grp; s < sp; s += 32) {
        const float4 vv = *(const float4*)(vbase + (size_t)s * HD + sl * 4);
        const float4 pp = *(const float4*)&sc[(size_t)s * 4];  // group-broadcast
        o[0][0] += pp.x * vv.x; o[0][1] += pp.x * vv.y; o[0][2] += pp.x * vv.z; o[0][3] += pp.x * vv.w;
        o[1][0] += pp.y * vv.x; o[1][1] += pp.y * vv.y; o[1][2] += pp.y * vv.z; o[1][3] += pp.y * vv.w;
        o[2][0] += pp.z * vv.x; o[2][1] += pp.z * vv.y; o[2][2] += pp.z * vv.z; o[2][3] += pp.z * vv.w;
        o[3][0] += pp.w * vv.x; o[3][1] += pp.w * vv.y; o[3][2] += pp.w * vv.z; o[3][3] += pp.w * vv.w;
    }
    if ((sp & 31) == grp) {  // the new V row, owned by exactly one group
        const float4 pp = *(const float4*)&sc[(size_t)sp * 4];
        const float4 vv = *(const float4*)&v_s[sl * 4];
        o[0][0] += pp.x * vv.x; o[0][1] += pp.x * vv.y; o[0][2] += pp.x * vv.z; o[0][3] += pp.x * vv.w;
        o[1][0] += pp.y * vv.x; o[1][1] += pp.y * vv.y; o[1][2] += pp.y * vv.z; o[1][3] += pp.y * vv.w;
        o[2][0] += pp.z * vv.x; o[2][1] += pp.z * vv.y; o[2][2] += pp.z * vv.z; o[2][3] += pp.z * vv.w;
        o[3][0] += pp.w * vv.x; o[3][1] += pp.w * vv.y; o[3][2] += pp.w * vv.z; o[3][3] += pp.w * vv.w;
    }

    // fold the two 32-lane halves of each wave in-register
#pragma unroll
    for (int h = 0; h < 4; ++h)
#pragma unroll
        for (int c = 0; c < 4; ++c) o[h][c] += __shfl_xor(o[h][c], 32);

    __syncthreads();  // all prob reads done; reuse sc as reduction buffer

    if (half == 0) {
#pragma unroll
        for (int h = 0; h < 4; ++h)
            *(float4*)&sc[w * 512 + h * 128 + sl * 4] =
                make_float4(o[h][0], o[h][1], o[h][2], o[h][3]);
    }
    __syncthreads();

    for (int step = 8; step >= 1; step >>= 1) {
        if (w < step) {
#pragma unroll
            for (int i = 0; i < 8; ++i) {
                int j = lane + i * 64;
                sc[w * 512 + j] += sc[(w + step) * 512 + j];
            }
        }
        __syncthreads();
    }

    if (t < 512) {
        int h = t >> 7, d = t & 127;
        attn[(size_t)b * DIM + (g * 4 + h) * 128 + d] = sc[h * 128 + d] * s_inv[h];
    }
}

// ---------------------------------------------------------------------------
// Kernel: final reduce of output-projection partials.  grid 512, block 256.
// ---------------------------------------------------------------------------
__global__ void out_reduce(const float* __restrict__ part, float* __restrict__ out) {
    const int e = blockIdx.x * 256 + threadIdx.x;
    float s = 0.f;
    for (int kc = 0; kc < 32; ++kc) s += part[(size_t)kc * 32 * DIM + e];
    out[e] = s;
}

// ---------------------------------------------------------------------------
extern "C" void kernel_launch(void* const* d_in, const int* in_sizes, int n_in,
                              void* d_out, int out_size, void* d_ws, size_t ws_size,
                              hipStream_t stream) {
    const float* x       = (const float*)d_in[0];
    const float* wqkv    = (const float*)d_in[1];
    const float* wo      = (const float*)d_in[2];
    const float* cache_k = (const float*)d_in[3];
    const float* cache_v = (const float*)d_in[4];
    const int*   sp      = (const int*)d_in[5];
    float* out = (float*)d_out;
    float* ws  = (float*)d_ws;

    // workspace layout (floats)
    float* part1  = ws;                       // 32*32*6144 = 6,291,456
    float* attn   = part1 + 6291456;          // 32*4096    =   131,072
    float* part2  = attn + 131072;            // 32*32*4096 = 4,194,304
    // total 10,616,832 floats = 42.5 MB

    gemm_partial<QKV_DIM><<<dim3(24, 32), 256, 0, stream>>>(x, wqkv, part1);
    attn_fused<<<256, 1024, 0, stream>>>(part1, cache_k, cache_v, sp, attn);
    gemm_partial<DIM><<<dim3(16, 32), 256, 0, stream>>>(attn, wo, part2);
    out_reduce<<<512, 256, 0, stream>>>(part2, out);
}